// Round 7
// baseline (794.943 us; speedup 1.0000x reference)
//
#include <hip/hip_runtime.h>
#include <math.h>

#define N_ROWS 12544   // 16*28*28
#define C_DIM  1536
#define M_ROWS 16384
#define BATCH  16

// quantization scale: q = round(16*v), dequant s = 1/16. No clipping for
// |v| < 7.9 (inputs are ~N(0,1), max |z| ~ 5.5). 2*s^2 = 0.0078125.
#define QS    16.0f
#define S2x2  0.0078125f   // 2 / (16*16)
#define S2    0.00390625f  // 1 / (16*16)

typedef int   i32x4 __attribute__((ext_vector_type(4)));
typedef unsigned char u8;
typedef signed char   i8;

// order-preserving float->uint key for atomicMin
__device__ __forceinline__ unsigned fkey(float f) {
  unsigned u = __float_as_uint(f);
  return (u & 0x80000000u) ? ~u : (u | 0x80000000u);
}
__device__ __forceinline__ float funkey(unsigned k) {
  unsigned u = (k & 0x80000000u) ? (k ^ 0x80000000u) : ~k;
  return __uint_as_float(u);
}

__device__ __forceinline__ void gl_lds16(const void* g, void* l) {
  __builtin_amdgcn_global_load_lds(
      (__attribute__((address_space(1))) void*)(g),
      (__attribute__((address_space(3))) void*)(l), 16, 0, 0);
}

__device__ __forceinline__ int quant(float v) {
  int q = __float2int_rn(v * QS);
  return max(-127, min(127, q));
}

#define FSTRIDE 528    // 512 + 16 padded LDS row stride (feature third-tile)

// ------- Kernel A (fused): features->i8 + x_sq | bank->i8 + m_sq ------------
// blocks [0, 1344): feature (b,y,third) blocks — 3-way channel split per
// pixel-row (512 channels each: feat2 | feat3 lo | feat3 hi). Each third
// writes its int square-sum partial to its own xsqp plane (no atomics, no
// memset needed); half==0 blocks also init dmin, block 0 inits score.
// blocks [1344, 1344+2048): memory-bank rows, ONE ROW PER WAVE, no barriers,
// 6 independent float4 loads per lane, fully coalesced.
__global__ __launch_bounds__(512) void prep_all(
    const float* __restrict__ feat2, const float* __restrict__ feat3,
    const float* __restrict__ mb,
    i8* __restrict__ feats, i8* __restrict__ mbb,
    int* __restrict__ xsqp, float* __restrict__ msq,
    unsigned* __restrict__ dmin, unsigned* __restrict__ score) {
  const int blk = blockIdx.x;
  const int t = threadIdx.x;
  __shared__ u8 fsm[28 * FSTRIDE];
  __shared__ int sxq[28];

  if (blk >= 1344) {
    // ---- memory bank: row per wave, lane covers 6 of 384 float4 ----
    const int wave = t >> 6, lane = t & 63;
    const int row = (blk - 1344) * 8 + wave;
    const float* in = mb + (size_t)row * C_DIM;
    i8* outp = mbb + (size_t)row * C_DIM;
    float ssq = 0.f;
#pragma unroll
    for (int i = 0; i < 6; i++) {
      const int f4 = lane + 64 * i;
      const float4 v = *(const float4*)(in + f4 * 4);
      int q0 = quant(v.x), q1 = quant(v.y), q2 = quant(v.z), q3 = quant(v.w);
      unsigned w = (unsigned)(q0 & 0xFF) | ((unsigned)(q1 & 0xFF) << 8)
                 | ((unsigned)(q2 & 0xFF) << 16) | ((unsigned)(q3 & 0xFF) << 24);
      *(unsigned*)(outp + f4 * 4) = w;
      ssq += (float)(q0*q0 + q1*q1 + q2*q2 + q3*q3);
    }
    for (int off = 32; off > 0; off >>= 1) ssq += __shfl_down(ssq, off, 64);
    if (lane == 0) msq[row] = S2 * ssq;
  } else {
    // ---- feature block: (pixel-row p, channel-third half) ----
    const int half = blk % 3, p = blk / 3;
    const int b = p / 28, y = p % 28;
    const int n0 = b * 784 + y * 28;

    // y-interp constants (shared by whole block)
    const float sy = 0.5f * y - 0.25f;
    const int y0 = (int)floorf(sy); const float fy = sy - (float)y0;
    const int y0c = max(y0, 0), y1c = min(y0 + 1, 13);
    const float wy0 = 1.f - fy, wy1 = fy;

    const int g  = t >> 5;      // 16 groups of 32
    const int l2 = t & 31;
    // per-lane x-interp constants (x = l2 for l2 < 28)
    const float sx = 0.5f * l2 - 0.25f;
    const int x0 = (int)floorf(sx); const float fx = sx - (float)x0;
    const int x0c = max(x0, 0), x1c = min(x0 + 1, 13);
    const float wx0 = 1.f - fx, wx1 = fx;

    if (t < 28) sxq[t] = 0;

    if (half == 0) {
      // feat2 (c = 0..511), group g handles c = i*16 + g
      const float* f2b = feat2 + (size_t)b * 512 * 784 + y * 28;
#pragma unroll 4
      for (int i = 0; i < 32; i++) {
        const int c = i * 16 + g;
        if (l2 < 28) {
          float v = f2b[(size_t)c * 784 + l2];
          fsm[l2 * FSTRIDE + c] = (u8)(i8)quant(v);
        }
      }
    } else {
      // feat3 bilinear, 512 channels: cc0 = (half-1)*512
      const int cc0 = (half - 1) * 512;
      const float* f3b = feat3 + (size_t)b * 1024 * 196;
#pragma unroll 4
      for (int i = 0; i < 32; i++) {
        const int cc = cc0 + i * 16 + g;
        const float* f3 = f3b + (size_t)cc * 196;
        float v = 0.f;
        if (l2 < 14)       v = f3[y0c * 14 + l2];
        else if (l2 < 28)  v = f3[y1c * 14 + (l2 - 14)];
        // redistribute: lane x needs row0/row1 at x0c, x1c
        float t0 = wy0 * __shfl(v, x0c, 32)     + wy1 * __shfl(v, 14 + x0c, 32);
        float t1 = wy0 * __shfl(v, x1c, 32)     + wy1 * __shfl(v, 14 + x1c, 32);
        if (l2 < 28) {
          float o = wx0 * t0 + wx1 * t1;
          fsm[l2 * FSTRIDE + (i * 16 + g)] = (u8)(i8)quant(o);
        }
      }
    }
    __syncthreads();

    // coalesced 16B writes of this 512-channel slice + exact int sq-sums
    const int c0 = half * 512;
    i8* orow = feats + (size_t)n0 * C_DIM + c0;
    for (int idx = t; idx < 28 * 32; idx += 512) {
      const int row = idx / 32, col = idx % 32;
      i32x4 wv = *(const i32x4*)(fsm + row * FSTRIDE + col * 16);
      *(i32x4*)(orow + (size_t)row * C_DIM + col * 16) = wv;
      int s = 0;
#pragma unroll
      for (int k = 0; k < 4; k++) {
        const int w = wv[k];
        const int b0 = (int)(i8)(w & 0xFF), b1 = (int)(i8)((w >> 8) & 0xFF);
        const int b2 = (int)(i8)((w >> 16) & 0xFF), b3 = (int)(i8)(w >> 24);
        s += b0*b0 + b1*b1 + b2*b2 + b3*b3;
      }
      atomicAdd(&sxq[row], s);
    }
    __syncthreads();
    if (t < 28) {
      xsqp[half * N_ROWS + n0 + t] = sxq[t];      // own plane: no atomics
      if (half == 0) dmin[n0 + t] = 0xFFFFFFFFu;  // init before gemm
    }
    if (blk == 0 && t < BATCH) score[t] = 0u;     // values >= 0
  }
}

// ---------------- Kernel C: i8 MFMA GEMM + fused min over M -----------------
// 128x128 tile, BK=128, proven 2-barrier structure + XOR-swizzled A slabs +
// Gram K-chunk bijection + SGPR-only XCD bit-swap (r6: 342us, FETCH 106MB).
// NEW (r7): B operand BYPASSES LDS. r6 PMC analysis: LDS moved 96KB per
// block-K-step = 42 TB/s ~ 81% of b128-achievable -> LDS-BW-bound. The Gram
// bijection makes each lane's B fragment 16 CONTIGUOUS global bytes:
// Mb[(col0+wn*64+ni*16+l16)*1536 + k0 + sub*64 + quad*16]. Load it straight
// to VGPRs (8 dwordx4/lane/K-step, 16 cachelines each, XCD-resident 3MB
// slab) in parallel with A's gl_lds; same barrier drains both. LDS traffic
// halves (48KB: A write 16 + A read 32); B's 2x wave re-read moves to L1/L2
// where headroom is 2.5x. Cost: +32 VGPR for bf[2][4] -> 3 waves/SIMD
// (launch_bounds caps regs at 170 so we never fall to 2).
__global__ __launch_bounds__(256, 3) void gemm_min(
    const i8* __restrict__ X, const i8* __restrict__ Mb,
    const float* __restrict__ msq, unsigned* __restrict__ dmin) {
  __shared__ u8 As[16384];
  __shared__ unsigned smin[128];
  const int t = threadIdx.x;
  const int bx = blockIdx.x;
  const int mtile = ((bx & 7) << 4) | (bx >> 3);   // 0..127, SGPR-only swap
  const int ntile = blockIdx.y;                    // 0..97  over N
  const int lane = t & 63, wave = t >> 6;
  const int wm = wave >> 1, wn = wave & 1;
  if (t < 128) smin[t] = 0xFFFFFFFFu;

  const int row0 = ntile * 128;
  const int col0 = mtile * 128;
  // A staging: thread t fills slot (row=t>>2, slot=t&3) of a 64-row half;
  // global chunk c = (t&3) ^ ((t>>3)&3)
  const int s_row = t >> 2;
  const int s_ch  = (t & 3) ^ ((t >> 3) & 3);
  const i8* ga = X + (size_t)(row0 + s_row) * C_DIM + s_ch * 16;
  u8* la = As + t * 16;

  const int quad = lane >> 4, l16 = lane & 15;
  // per-lane B fragment base: row = col0 + wn*64 + l16 (+ni*16), bytes
  // [k0 + sub*64 + quad*16, +16) -- exactly the bytes the LDS path delivered
  const i8* gbf = Mb + (size_t)(col0 + wn * 64 + l16) * C_DIM + quad * 16;

  i32x4 acc[4][4];
  const i32x4 zero = {0, 0, 0, 0};
#pragma unroll
  for (int mi = 0; mi < 4; mi++)
#pragma unroll
    for (int ni = 0; ni < 4; ni++) acc[mi][ni] = zero;

  // A fragment read: slot (quad ^ fsw)*16 = global bytes [quad*16,+16)
  const int fsw = (l16 >> 1) & 3;
  const int slot = ((quad ^ fsw) * 16);
  const u8* arow = As + (wm * 64 + l16) * 64 + slot;   // sub1 at +8192

  for (int k0 = 0; k0 < C_DIM; k0 += 128) {
    __syncthreads();
    gl_lds16(ga + k0,                    la);
    gl_lds16(ga + 64 * C_DIM + k0,       la + 4096);
    gl_lds16(ga + k0 + 64,               la + 8192);
    gl_lds16(ga + 64 * C_DIM + k0 + 64,  la + 12288);
    i32x4 bf[2][4];
#pragma unroll
    for (int sub = 0; sub < 2; sub++)
#pragma unroll
      for (int ni = 0; ni < 4; ni++)
        bf[sub][ni] = *(const i32x4*)(gbf + ni * (16 * C_DIM) + k0 + sub * 64);
    __syncthreads();
#pragma unroll
    for (int sub = 0; sub < 2; sub++) {
      i32x4 af[4];
#pragma unroll
      for (int mi = 0; mi < 4; mi++)
        af[mi] = *(const i32x4*)(arow + sub * 8192 + mi * 1024);
#pragma unroll
      for (int mi = 0; mi < 4; mi++)
#pragma unroll
        for (int ni = 0; ni < 4; ni++)
          acc[mi][ni] = __builtin_amdgcn_mfma_i32_16x16x64_i8(
              af[mi], bf[sub][ni], acc[mi][ni], 0, 0, 0);
    }
  }

  // epilogue: v = m_sq[j] - 2*s^2*dot ; min over this block's 128-col slab
  float msql[4];
#pragma unroll
  for (int ni = 0; ni < 4; ni++)
    msql[ni] = msq[col0 + wn * 64 + ni * 16 + l16];

#pragma unroll
  for (int mi = 0; mi < 4; mi++) {
#pragma unroll
    for (int r = 0; r < 4; r++) {
      float v = msql[0] - S2x2 * (float)acc[mi][0][r];
#pragma unroll
      for (int ni = 1; ni < 4; ni++)
        v = fminf(v, msql[ni] - S2x2 * (float)acc[mi][ni][r]);
      v = fminf(v, __shfl_xor(v, 1, 64));
      v = fminf(v, __shfl_xor(v, 2, 64));
      v = fminf(v, __shfl_xor(v, 4, 64));
      v = fminf(v, __shfl_xor(v, 8, 64));
      if (l16 == 0) {
        int lrow = wm * 64 + mi * 16 + quad * 4 + r;  // C/D: row = quad*4 + reg
        atomicMin(&smin[lrow], fkey(v));
      }
    }
  }
  __syncthreads();
  if (t < 128) atomicMin(&dmin[row0 + t], smin[t]);
}

// ------- Kernel D: sqrt + 28->224 bilinear + per-image max (16x8 blocks) ----
__global__ void finalize(const unsigned* __restrict__ dmin,
                         const int* __restrict__ xsqp,
                         float* __restrict__ out) {
  const int b = blockIdx.x, slice = blockIdx.y, t = threadIdx.x;
  __shared__ float smap[784];
  __shared__ float sred[4];
  for (int i = t; i < 784; i += 256) {
    const int idx = b * 784 + i;
    const int xs = xsqp[idx] + xsqp[N_ROWS + idx] + xsqp[2 * N_ROWS + idx];
    float d2 = S2 * (float)xs + funkey(dmin[idx]);
    smap[i] = sqrtf(fmaxf(d2, 0.f));
  }
  __syncthreads();
  float* omap = out + (size_t)b * 50176;
  float tmax = 0.f;
  const int p0 = slice * 6272;           // 28 output rows per slice
  for (int p = p0 + t; p < p0 + 6272; p += 256) {
    const int Y = p / 224, Xp = p % 224;
    const float sy = Y * 0.125f - 0.4375f;   // (dst+0.5)/8 - 0.5
    const float sx = Xp * 0.125f - 0.4375f;
    const int y0 = (int)floorf(sy); const float fy = sy - (float)y0;
    const int x0 = (int)floorf(sx); const float fx = sx - (float)x0;
    const int y0c = max(y0, 0), y1c = min(y0 + 1, 27);
    const int x0c = max(x0, 0), x1c = min(x0 + 1, 27);
    float v = (1.f-fy)*((1.f-fx)*smap[y0c*28+x0c] + fx*smap[y0c*28+x1c])
            +      fy *((1.f-fx)*smap[y1c*28+x0c] + fx*smap[y1c*28+x1c]);
    omap[p] = v;
    tmax = fmaxf(tmax, v);
  }
  for (int off = 32; off > 0; off >>= 1)
    tmax = fmaxf(tmax, __shfl_down(tmax, off, 64));
  if ((t & 63) == 0) sred[t >> 6] = tmax;
  __syncthreads();
  if (t == 0) {
    float m = fmaxf(fmaxf(sred[0], sred[1]), fmaxf(sred[2], sred[3]));
    // values >= 0: uint bit-pattern order == float order
    atomicMax((unsigned*)(out + 802816 + b), __float_as_uint(m));
  }
}

extern "C" void kernel_launch(void* const* d_in, const int* in_sizes, int n_in,
                              void* d_out, int out_size, void* d_ws, size_t ws_size,
                              hipStream_t stream) {
  const float* feat2 = (const float*)d_in[0];  // [16,512,28,28]
  const float* feat3 = (const float*)d_in[1];  // [16,1024,14,14]
  const float* mb    = (const float*)d_in[2];  // [16384,1536]
  char* ws = (char*)d_ws;
  i8*       feats = (i8*)ws;                           // 12544*1536 = 19,267,584
  i8*       mbb   = (i8*)(ws + 19267584);              // 16384*1536 = 25,165,824
  int*      xsqp  = (int*)(ws + 44433408);             // 3*12544*4 = 150,528
  float*    msq   = (float*)(ws + 44583936);           // 16384*4
  unsigned* dmin  = (unsigned*)(ws + 44649472);        // 12544*4
  float* out = (float*)d_out;

  prep_all<<<1344 + 2048, 512, 0, stream>>>(
      feat2, feat3, mb, feats, mbb, xsqp, msq, dmin,
      (unsigned*)(out + 802816));
  gemm_min<<<dim3(128, 98), 256, 0, stream>>>(feats, mbb, msq, dmin);
  finalize<<<dim3(BATCH, 8), 256, 0, stream>>>(dmin, xsqp, out);
}

// Round 8
// 507.440 us; speedup vs baseline: 1.5666x; 1.5666x over previous
//
#include <hip/hip_runtime.h>
#include <math.h>

#define N_ROWS 12544   // 16*28*28
#define C_DIM  1536
#define M_ROWS 16384
#define BATCH  16

// quantization scale: q = round(16*v), dequant s = 1/16. No clipping for
// |v| < 7.9 (inputs are ~N(0,1), max |z| ~ 5.5). 2*s^2 = 0.0078125.
#define QS    16.0f
#define S2x2  0.0078125f   // 2 / (16*16)
#define S2    0.00390625f  // 1 / (16*16)

typedef int   i32x4 __attribute__((ext_vector_type(4)));
typedef unsigned char u8;
typedef signed char   i8;

// order-preserving float->uint key for atomicMin
__device__ __forceinline__ unsigned fkey(float f) {
  unsigned u = __float_as_uint(f);
  return (u & 0x80000000u) ? ~u : (u | 0x80000000u);
}
__device__ __forceinline__ float funkey(unsigned k) {
  unsigned u = (k & 0x80000000u) ? (k ^ 0x80000000u) : ~k;
  return __uint_as_float(u);
}

__device__ __forceinline__ void gl_lds16(const void* g, void* l) {
  __builtin_amdgcn_global_load_lds(
      (__attribute__((address_space(1))) void*)(g),
      (__attribute__((address_space(3))) void*)(l), 16, 0, 0);
}

__device__ __forceinline__ int quant(float v) {
  int q = __float2int_rn(v * QS);
  return max(-127, min(127, q));
}

#define FSTRIDE 528    // 512 + 16 padded LDS row stride (feature third-tile)

// ------- Kernel A (fused): features->i8 + x_sq | bank->i8 + m_sq ------------
// PROVEN r7 version (non-gemm time 127.5us): no memsets, xsq partials to
// per-third planes (no atomics), dmin/score inits folded in.
// blocks [0, 1344): feature (b,y,third) blocks — 3-way channel split per
// pixel-row (512 channels each: feat2 | feat3 lo | feat3 hi).
// blocks [1344, 1344+2048): memory-bank rows, ONE ROW PER WAVE, no barriers,
// 6 independent float4 loads per lane, fully coalesced.
__global__ __launch_bounds__(512) void prep_all(
    const float* __restrict__ feat2, const float* __restrict__ feat3,
    const float* __restrict__ mb,
    i8* __restrict__ feats, i8* __restrict__ mbb,
    int* __restrict__ xsqp, float* __restrict__ msq,
    unsigned* __restrict__ dmin, unsigned* __restrict__ score) {
  const int blk = blockIdx.x;
  const int t = threadIdx.x;
  __shared__ u8 fsm[28 * FSTRIDE];
  __shared__ int sxq[28];

  if (blk >= 1344) {
    // ---- memory bank: row per wave, lane covers 6 of 384 float4 ----
    const int wave = t >> 6, lane = t & 63;
    const int row = (blk - 1344) * 8 + wave;
    const float* in = mb + (size_t)row * C_DIM;
    i8* outp = mbb + (size_t)row * C_DIM;
    float ssq = 0.f;
#pragma unroll
    for (int i = 0; i < 6; i++) {
      const int f4 = lane + 64 * i;
      const float4 v = *(const float4*)(in + f4 * 4);
      int q0 = quant(v.x), q1 = quant(v.y), q2 = quant(v.z), q3 = quant(v.w);
      unsigned w = (unsigned)(q0 & 0xFF) | ((unsigned)(q1 & 0xFF) << 8)
                 | ((unsigned)(q2 & 0xFF) << 16) | ((unsigned)(q3 & 0xFF) << 24);
      *(unsigned*)(outp + f4 * 4) = w;
      ssq += (float)(q0*q0 + q1*q1 + q2*q2 + q3*q3);
    }
    for (int off = 32; off > 0; off >>= 1) ssq += __shfl_down(ssq, off, 64);
    if (lane == 0) msq[row] = S2 * ssq;
  } else {
    // ---- feature block: (pixel-row p, channel-third half) ----
    const int half = blk % 3, p = blk / 3;
    const int b = p / 28, y = p % 28;
    const int n0 = b * 784 + y * 28;

    // y-interp constants (shared by whole block)
    const float sy = 0.5f * y - 0.25f;
    const int y0 = (int)floorf(sy); const float fy = sy - (float)y0;
    const int y0c = max(y0, 0), y1c = min(y0 + 1, 13);
    const float wy0 = 1.f - fy, wy1 = fy;

    const int g  = t >> 5;      // 16 groups of 32
    const int l2 = t & 31;
    // per-lane x-interp constants (x = l2 for l2 < 28)
    const float sx = 0.5f * l2 - 0.25f;
    const int x0 = (int)floorf(sx); const float fx = sx - (float)x0;
    const int x0c = max(x0, 0), x1c = min(x0 + 1, 13);
    const float wx0 = 1.f - fx, wx1 = fx;

    if (t < 28) sxq[t] = 0;

    if (half == 0) {
      // feat2 (c = 0..511), group g handles c = i*16 + g
      const float* f2b = feat2 + (size_t)b * 512 * 784 + y * 28;
#pragma unroll 4
      for (int i = 0; i < 32; i++) {
        const int c = i * 16 + g;
        if (l2 < 28) {
          float v = f2b[(size_t)c * 784 + l2];
          fsm[l2 * FSTRIDE + c] = (u8)(i8)quant(v);
        }
      }
    } else {
      // feat3 bilinear, 512 channels: cc0 = (half-1)*512
      const int cc0 = (half - 1) * 512;
      const float* f3b = feat3 + (size_t)b * 1024 * 196;
#pragma unroll 4
      for (int i = 0; i < 32; i++) {
        const int cc = cc0 + i * 16 + g;
        const float* f3 = f3b + (size_t)cc * 196;
        float v = 0.f;
        if (l2 < 14)       v = f3[y0c * 14 + l2];
        else if (l2 < 28)  v = f3[y1c * 14 + (l2 - 14)];
        // redistribute: lane x needs row0/row1 at x0c, x1c
        float t0 = wy0 * __shfl(v, x0c, 32)     + wy1 * __shfl(v, 14 + x0c, 32);
        float t1 = wy0 * __shfl(v, x1c, 32)     + wy1 * __shfl(v, 14 + x1c, 32);
        if (l2 < 28) {
          float o = wx0 * t0 + wx1 * t1;
          fsm[l2 * FSTRIDE + (i * 16 + g)] = (u8)(i8)quant(o);
        }
      }
    }
    __syncthreads();

    // coalesced 16B writes of this 512-channel slice + exact int sq-sums
    const int c0 = half * 512;
    i8* orow = feats + (size_t)n0 * C_DIM + c0;
    for (int idx = t; idx < 28 * 32; idx += 512) {
      const int row = idx / 32, col = idx % 32;
      i32x4 wv = *(const i32x4*)(fsm + row * FSTRIDE + col * 16);
      *(i32x4*)(orow + (size_t)row * C_DIM + col * 16) = wv;
      int s = 0;
#pragma unroll
      for (int k = 0; k < 4; k++) {
        const int w = wv[k];
        const int b0 = (int)(i8)(w & 0xFF), b1 = (int)(i8)((w >> 8) & 0xFF);
        const int b2 = (int)(i8)((w >> 16) & 0xFF), b3 = (int)(i8)(w >> 24);
        s += b0*b0 + b1*b1 + b2*b2 + b3*b3;
      }
      atomicAdd(&sxq[row], s);
    }
    __syncthreads();
    if (t < 28) {
      xsqp[half * N_ROWS + n0 + t] = sxq[t];      // own plane: no atomics
      if (half == 0) dmin[n0 + t] = 0xFFFFFFFFu;  // init before gemm
    }
    if (blk == 0 && t < BATCH) score[t] = 0u;     // values >= 0
  }
}

// ---------------- Kernel C: i8 MFMA GEMM + fused min over M -----------------
// PROVEN r6 version, byte-identical (342.4us +-0.2 across 5 dispatches):
// 128x128 tile, BK=128 (two 64B sub-slabs per row), XOR-swizzled LDS per 64B
// slab (zero-conflict), mfma_i32_16x16x64_i8 (K=64 = one slab -> ONE b128
// per fragment per MFMA), Gram K-chunk bijection (A and B share the lane->k
// map so the contraction is exact). 64 VGPR + 64 AGPR, 33 KB LDS -> 4
// blocks/CU; co-resident blocks hide the barrier drains (r1/r3/r5/r7: every
// structure trading this away regressed). SGPR-only XCD bit-swap keeps each
// XCD's 16-mtile B-slab (3 MB) L2-resident (FETCH 435->106 MB).
__global__ void gemm_min(const i8* __restrict__ X, const i8* __restrict__ Mb,
                         const float* __restrict__ msq,
                         unsigned* __restrict__ dmin) {
  __shared__ u8 As[16384];
  __shared__ u8 Bs[16384];
  __shared__ unsigned smin[128];
  const int t = threadIdx.x;
  const int bx = blockIdx.x;
  const int mtile = ((bx & 7) << 4) | (bx >> 3);   // 0..127, SGPR-only swap
  const int ntile = blockIdx.y;                    // 0..97  over N
  const int lane = t & 63, wave = t >> 6;
  const int wm = wave >> 1, wn = wave & 1;
  if (t < 128) smin[t] = 0xFFFFFFFFu;

  const int row0 = ntile * 128;
  const int col0 = mtile * 128;
  // staging: thread t fills slot (row=t>>2, slot=t&3) of a 64-row half;
  // global chunk c = (t&3) ^ ((t>>3)&3)
  const int s_row = t >> 2;
  const int s_ch  = (t & 3) ^ ((t >> 3) & 3);
  const i8* ga = X  + (size_t)(row0 + s_row) * C_DIM + s_ch * 16;
  const i8* gb = Mb + (size_t)(col0 + s_row) * C_DIM + s_ch * 16;
  u8* la = As + t * 16;
  u8* lb = Bs + t * 16;

  i32x4 acc[4][4];
  const i32x4 zero = {0, 0, 0, 0};
#pragma unroll
  for (int mi = 0; mi < 4; mi++)
#pragma unroll
    for (int ni = 0; ni < 4; ni++) acc[mi][ni] = zero;

  const int quad = lane >> 4, l16 = lane & 15;
  // one b128 per (row16, sub): slot (quad ^ fsw)*16 = global bytes
  // [quad*16, quad*16+16) of that row's 64B slab
  const int fsw = (l16 >> 1) & 3;
  const int slot = ((quad ^ fsw) * 16);
  const u8* arow = As + (wm * 64 + l16) * 64 + slot;   // sub1 at +8192
  const u8* brow = Bs + (wn * 64 + l16) * 64 + slot;

  for (int k0 = 0; k0 < C_DIM; k0 += 128) {
    __syncthreads();
    gl_lds16(ga + k0,                    la);
    gl_lds16(ga + 64 * C_DIM + k0,       la + 4096);
    gl_lds16(ga + k0 + 64,               la + 8192);
    gl_lds16(ga + 64 * C_DIM + k0 + 64,  la + 12288);
    gl_lds16(gb + k0,                    lb);
    gl_lds16(gb + 64 * C_DIM + k0,       lb + 4096);
    gl_lds16(gb + k0 + 64,               lb + 8192);
    gl_lds16(gb + 64 * C_DIM + k0 + 64,  lb + 12288);
    __syncthreads();
#pragma unroll
    for (int sub = 0; sub < 2; sub++) {
      i32x4 af[4], bf[4];
#pragma unroll
      for (int mi = 0; mi < 4; mi++)
        af[mi] = *(const i32x4*)(arow + sub * 8192 + mi * 1024);
#pragma unroll
      for (int ni = 0; ni < 4; ni++)
        bf[ni] = *(const i32x4*)(brow + sub * 8192 + ni * 1024);
#pragma unroll
      for (int mi = 0; mi < 4; mi++)
#pragma unroll
        for (int ni = 0; ni < 4; ni++)
          acc[mi][ni] = __builtin_amdgcn_mfma_i32_16x16x64_i8(
              af[mi], bf[ni], acc[mi][ni], 0, 0, 0);
    }
  }

  // epilogue: v = m_sq[j] - 2*s^2*dot ; min over this block's 128-col slab
  float msql[4];
#pragma unroll
  for (int ni = 0; ni < 4; ni++)
    msql[ni] = msq[col0 + wn * 64 + ni * 16 + l16];

#pragma unroll
  for (int mi = 0; mi < 4; mi++) {
#pragma unroll
    for (int r = 0; r < 4; r++) {
      float v = msql[0] - S2x2 * (float)acc[mi][0][r];
#pragma unroll
      for (int ni = 1; ni < 4; ni++)
        v = fminf(v, msql[ni] - S2x2 * (float)acc[mi][ni][r]);
      v = fminf(v, __shfl_xor(v, 1, 64));
      v = fminf(v, __shfl_xor(v, 2, 64));
      v = fminf(v, __shfl_xor(v, 4, 64));
      v = fminf(v, __shfl_xor(v, 8, 64));
      if (l16 == 0) {
        int lrow = wm * 64 + mi * 16 + quad * 4 + r;  // C/D: row = quad*4 + reg
        atomicMin(&smin[lrow], fkey(v));
      }
    }
  }
  __syncthreads();
  if (t < 128) atomicMin(&dmin[row0 + t], smin[t]);
}

// ------- Kernel D: sqrt + 28->224 bilinear + per-image max (16x8 blocks) ----
__global__ void finalize(const unsigned* __restrict__ dmin,
                         const int* __restrict__ xsqp,
                         float* __restrict__ out) {
  const int b = blockIdx.x, slice = blockIdx.y, t = threadIdx.x;
  __shared__ float smap[784];
  __shared__ float sred[4];
  for (int i = t; i < 784; i += 256) {
    const int idx = b * 784 + i;
    const int xs = xsqp[idx] + xsqp[N_ROWS + idx] + xsqp[2 * N_ROWS + idx];
    float d2 = S2 * (float)xs + funkey(dmin[idx]);
    smap[i] = sqrtf(fmaxf(d2, 0.f));
  }
  __syncthreads();
  float* omap = out + (size_t)b * 50176;
  float tmax = 0.f;
  const int p0 = slice * 6272;           // 28 output rows per slice
  for (int p = p0 + t; p < p0 + 6272; p += 256) {
    const int Y = p / 224, Xp = p % 224;
    const float sy = Y * 0.125f - 0.4375f;   // (dst+0.5)/8 - 0.5
    const float sx = Xp * 0.125f - 0.4375f;
    const int y0 = (int)floorf(sy); const float fy = sy - (float)y0;
    const int x0 = (int)floorf(sx); const float fx = sx - (float)x0;
    const int y0c = max(y0, 0), y1c = min(y0 + 1, 27);
    const int x0c = max(x0, 0), x1c = min(x0 + 1, 27);
    float v = (1.f-fy)*((1.f-fx)*smap[y0c*28+x0c] + fx*smap[y0c*28+x1c])
            +      fy *((1.f-fx)*smap[y1c*28+x0c] + fx*smap[y1c*28+x1c]);
    omap[p] = v;
    tmax = fmaxf(tmax, v);
  }
  for (int off = 32; off > 0; off >>= 1)
    tmax = fmaxf(tmax, __shfl_down(tmax, off, 64));
  if ((t & 63) == 0) sred[t >> 6] = tmax;
  __syncthreads();
  if (t == 0) {
    float m = fmaxf(fmaxf(sred[0], sred[1]), fmaxf(sred[2], sred[3]));
    // values >= 0: uint bit-pattern order == float order
    atomicMax((unsigned*)(out + 802816 + b), __float_as_uint(m));
  }
}

extern "C" void kernel_launch(void* const* d_in, const int* in_sizes, int n_in,
                              void* d_out, int out_size, void* d_ws, size_t ws_size,
                              hipStream_t stream) {
  const float* feat2 = (const float*)d_in[0];  // [16,512,28,28]
  const float* feat3 = (const float*)d_in[1];  // [16,1024,14,14]
  const float* mb    = (const float*)d_in[2];  // [16384,1536]
  char* ws = (char*)d_ws;
  i8*       feats = (i8*)ws;                           // 12544*1536 = 19,267,584
  i8*       mbb   = (i8*)(ws + 19267584);              // 16384*1536 = 25,165,824
  int*      xsqp  = (int*)(ws + 44433408);             // 3*12544*4 = 150,528
  float*    msq   = (float*)(ws + 44583936);           // 16384*4
  unsigned* dmin  = (unsigned*)(ws + 44649472);        // 12544*4
  float* out = (float*)d_out;

  prep_all<<<1344 + 2048, 512, 0, stream>>>(
      feat2, feat3, mb, feats, mbb, xsqp, msq, dmin,
      (unsigned*)(out + 802816));
  gemm_min<<<dim3(128, 98), 256, 0, stream>>>(feats, mbb, msq, dmin);
  finalize<<<dim3(BATCH, 8), 256, 0, stream>>>(dmin, xsqp, out);
}